// Round 1
// baseline (415.448 us; speedup 1.0000x reference)
//
#include <hip/hip_runtime.h>
#include <hip/hip_bf16.h>

#define N_DIM 8192
#define E_DIM 2048
#define BM 128
#define BN 128
#define BK 32

typedef __bf16 bf16x8 __attribute__((ext_vector_type(8)));
typedef float  f32x4  __attribute__((ext_vector_type(4)));
typedef short  short8 __attribute__((ext_vector_type(8)));

// ---------------- conversion: A fp32 [N,E] -> bf16 [N,E] ----------------
__global__ __launch_bounds__(256) void cvtA(const float* __restrict__ A,
                                            __hip_bfloat16* __restrict__ Abf) {
    size_t i = ((size_t)blockIdx.x * 256 + threadIdx.x) * 8;
    float4 f0 = *reinterpret_cast<const float4*>(A + i);
    float4 f1 = *reinterpret_cast<const float4*>(A + i + 4);
    union { short8 s8; __hip_bfloat16 h[8]; } u;
    u.h[0] = __float2bfloat16(f0.x);
    u.h[1] = __float2bfloat16(f0.y);
    u.h[2] = __float2bfloat16(f0.z);
    u.h[3] = __float2bfloat16(f0.w);
    u.h[4] = __float2bfloat16(f1.x);
    u.h[5] = __float2bfloat16(f1.y);
    u.h[6] = __float2bfloat16(f1.z);
    u.h[7] = __float2bfloat16(f1.w);
    *reinterpret_cast<short8*>(&Abf[i]) = u.s8;
}

// ------- scale+transpose: Bt[n,e] = W[e] * B[e,n], fp32 -> bf16 ---------
__global__ __launch_bounds__(256) void cvtB(const float* __restrict__ B,
                                            const float* __restrict__ W,
                                            __hip_bfloat16* __restrict__ Bt) {
    __shared__ float tile[32][33];
    const int tx = threadIdx.x & 31;
    const int ty = threadIdx.x >> 5;           // 0..7
    const int n0 = blockIdx.x * 32;            // N tiles (256)
    const int e0 = blockIdx.y * 32;            // E tiles (64)
#pragma unroll
    for (int r = 0; r < 4; ++r) {
        int e = e0 + ty + r * 8;
        tile[ty + r * 8][tx] = B[(size_t)e * N_DIM + n0 + tx] * W[e];
    }
    __syncthreads();
#pragma unroll
    for (int r = 0; r < 4; ++r) {
        int n = n0 + ty + r * 8;
        Bt[(size_t)n * E_DIM + e0 + tx] = __float2bfloat16(tile[tx][ty + r * 8]);
    }
}

// ---------------- GEMM: C[N,N] = Abf[N,E] * Btbf[N,E]^T ----------------
// m97 structure: 128x128 tile, BK=32, 4 waves (2x2), 16x16x32 bf16 MFMA,
// global_load_lds width-16 staging, 2 barriers per K-step.
__global__ __launch_bounds__(256) void gemm_bt(const __hip_bfloat16* __restrict__ A,
                                               const __hip_bfloat16* __restrict__ Bt,
                                               float* __restrict__ C) {
    __shared__ __align__(16) __hip_bfloat16 As[BM * BK];
    __shared__ __align__(16) __hip_bfloat16 Bs[BN * BK];

    const int tid  = threadIdx.x;
    const int lane = tid & 63;
    const int wave = tid >> 6;
    const int wm = wave >> 1, wn = wave & 1;

    const int tm = blockIdx.x / (N_DIM / BN);
    const int tn = blockIdx.x % (N_DIM / BN);

    // staging granules: 16B each; granule g = row*4 + colg; thread handles g=tid and g=tid+256
    const int rowg = tid >> 2;     // 0..63
    const int colg = tid & 3;

    const char* aP0 = (const char*)A  + ((size_t)(tm * BM + rowg) * E_DIM + colg * 8) * 2;
    const char* aP1 = aP0 + (size_t)64 * E_DIM * 2;
    const char* bP0 = (const char*)Bt + ((size_t)(tn * BN + rowg) * E_DIM + colg * 8) * 2;
    const char* bP1 = bP0 + (size_t)64 * E_DIM * 2;

    char* ldsA = (char*)As;
    char* ldsB = (char*)Bs;
    const unsigned base0 = wave * 1024;        // chunk 0: rows 0..63
    const unsigned base1 = 4096 + wave * 1024; // chunk 1: rows 64..127

    f32x4 acc[4][4] = {};

    const int fr = lane & 15;             // fragment row/col within 16
    const int kp = (lane >> 4) * 8;       // k offset within BK

    for (int kt = 0; kt < E_DIM / BK; ++kt) {
        __syncthreads();   // previous iteration's LDS reads complete
        __builtin_amdgcn_global_load_lds((const __attribute__((address_space(1))) void*)aP0,
                                         (__attribute__((address_space(3))) void*)(ldsA + base0), 16, 0, 0);
        __builtin_amdgcn_global_load_lds((const __attribute__((address_space(1))) void*)aP1,
                                         (__attribute__((address_space(3))) void*)(ldsA + base1), 16, 0, 0);
        __builtin_amdgcn_global_load_lds((const __attribute__((address_space(1))) void*)bP0,
                                         (__attribute__((address_space(3))) void*)(ldsB + base0), 16, 0, 0);
        __builtin_amdgcn_global_load_lds((const __attribute__((address_space(1))) void*)bP1,
                                         (__attribute__((address_space(3))) void*)(ldsB + base1), 16, 0, 0);
        aP0 += BK * 2; aP1 += BK * 2; bP0 += BK * 2; bP1 += BK * 2;
        __syncthreads();   // staging complete (compiler drains vmcnt before barrier)

        bf16x8 af[4], bfr[4];
#pragma unroll
        for (int mi = 0; mi < 4; ++mi)
            af[mi] = *reinterpret_cast<const bf16x8*>(ldsA + (wm * 64 + mi * 16 + fr) * (BK * 2) + kp * 2);
#pragma unroll
        for (int ni = 0; ni < 4; ++ni)
            bfr[ni] = *reinterpret_cast<const bf16x8*>(ldsB + (wn * 64 + ni * 16 + fr) * (BK * 2) + kp * 2);
#pragma unroll
        for (int mi = 0; mi < 4; ++mi)
#pragma unroll
            for (int ni = 0; ni < 4; ++ni)
                acc[mi][ni] = __builtin_amdgcn_mfma_f32_16x16x32_bf16(af[mi], bfr[ni], acc[mi][ni], 0, 0, 0);
    }

    // epilogue: C/D layout col = lane&15, row = (lane>>4)*4 + j  [m89-verified]
    const int crow0 = tm * BM + wm * 64 + (lane >> 4) * 4;
    const int ccol0 = tn * BN + wn * 64 + fr;
#pragma unroll
    for (int mi = 0; mi < 4; ++mi)
#pragma unroll
        for (int ni = 0; ni < 4; ++ni)
#pragma unroll
            for (int j = 0; j < 4; ++j)
                C[(size_t)(crow0 + mi * 16 + j) * N_DIM + (ccol0 + ni * 16)] = acc[mi][ni][j];
}

extern "C" void kernel_launch(void* const* d_in, const int* in_sizes, int n_in,
                              void* d_out, int out_size, void* d_ws, size_t ws_size,
                              hipStream_t stream) {
    const float* A = (const float*)d_in[0];   // DV2_H        [N, E]
    const float* B = (const float*)d_in[1];   // invDE_HT_DV2 [E, N]
    const float* W = (const float*)d_in[2];   // W            [E]
    float* C = (float*)d_out;                 // G            [N, N] fp32

    __hip_bfloat16* Abf  = (__hip_bfloat16*)d_ws;               // 32 MB
    __hip_bfloat16* Btbf = Abf + (size_t)N_DIM * E_DIM;         // 32 MB

    // A: 8192*2048 / 8 elems per thread / 256 threads = 8192 blocks
    cvtA<<<(N_DIM * (size_t)E_DIM) / 8 / 256, 256, 0, stream>>>(A, Abf);
    dim3 tgrid(N_DIM / 32, E_DIM / 32);
    cvtB<<<tgrid, 256, 0, stream>>>(B, W, Btbf);
    gemm_bt<<<(N_DIM / BM) * (N_DIM / BN), 256, 0, stream>>>(Abf, Btbf, C);
}

// Round 2
// 320.962 us; speedup vs baseline: 1.2944x; 1.2944x over previous
//
#include <hip/hip_runtime.h>
#include <hip/hip_bf16.h>

#define N_DIM 8192
#define E_DIM 2048
#define NT 64            // K tiles of BK=32

typedef __bf16 bf16x8 __attribute__((ext_vector_type(8)));
typedef float  f32x4  __attribute__((ext_vector_type(4)));
typedef short  short8 __attribute__((ext_vector_type(8)));

#define GLD(gp, lp) __builtin_amdgcn_global_load_lds( \
    (const __attribute__((address_space(1))) void*)(gp), \
    (__attribute__((address_space(3))) void*)(lp), 16, 0, 0)

// ---------------- conversion: A fp32 [N,E] -> bf16 [N,E] ----------------
__global__ __launch_bounds__(256) void cvtA(const float* __restrict__ A,
                                            __hip_bfloat16* __restrict__ Abf) {
    size_t i = ((size_t)blockIdx.x * 256 + threadIdx.x) * 8;
    float4 f0 = *reinterpret_cast<const float4*>(A + i);
    float4 f1 = *reinterpret_cast<const float4*>(A + i + 4);
    union { short8 s8; __hip_bfloat16 h[8]; } u;
    u.h[0] = __float2bfloat16(f0.x);
    u.h[1] = __float2bfloat16(f0.y);
    u.h[2] = __float2bfloat16(f0.z);
    u.h[3] = __float2bfloat16(f0.w);
    u.h[4] = __float2bfloat16(f1.x);
    u.h[5] = __float2bfloat16(f1.y);
    u.h[6] = __float2bfloat16(f1.z);
    u.h[7] = __float2bfloat16(f1.w);
    *reinterpret_cast<short8*>(&Abf[i]) = u.s8;
}

// ------- scale+transpose: Bt[n,e] = W[e] * B[e,n], fp32 -> bf16 ---------
__global__ __launch_bounds__(256) void cvtB(const float* __restrict__ B,
                                            const float* __restrict__ W,
                                            __hip_bfloat16* __restrict__ Bt) {
    __shared__ float tile[32][33];
    const int tx = threadIdx.x & 31;
    const int ty = threadIdx.x >> 5;
    const int n0 = blockIdx.x * 32;
    const int e0 = blockIdx.y * 32;
#pragma unroll
    for (int r = 0; r < 4; ++r) {
        int e = e0 + ty + r * 8;
        tile[ty + r * 8][tx] = B[(size_t)e * N_DIM + n0 + tx] * W[e];
    }
    __syncthreads();
#pragma unroll
    for (int r = 0; r < 4; ++r) {
        int n = n0 + ty + r * 8;
        Bt[(size_t)n * E_DIM + e0 + tx] = __float2bfloat16(tile[tx][ty + r * 8]);
    }
}

// ---------------- GEMM: C[N,N] = Abf[N,E] * Btbf[N,E]^T ----------------
// 256x256 tile, BK=32, 8 waves (2Mx4N), 4-deep LDS ring (128 KiB), counted
// vmcnt(8), XOR slot swizzle on LDS, setprio around MFMA clusters.
//
// LDS layout per tile buf (16 KiB for A, 16 KiB for B): 256 rows x 64 B.
// Row r holds k-slots s=0..3 (16 B each); physical slot = logical ^ ((r>>1)&3).
// Staging writes linearly (granule g: r=g>>2, s=g&3) with the INVERSE swizzle
// applied to the global source k-offset (involution, same XOR).

template<int VM, bool DOSTAGE>
__device__ __forceinline__ void ktile(char* ldsA, char* ldsB, int buf,
    int wm, int wn, int fr, int sp, int wave,
    const char*& aP0, const char*& aP1, const char*& bP0, const char*& bP1,
    f32x4 (&acc)[8][4])
{
    const char* At = ldsA + buf * 16384;
    const char* Bt = ldsB + buf * 16384;

    // ---- phase 0 ----
    asm volatile("s_waitcnt vmcnt(%0)" :: "n"(VM) : "memory"); // tile `buf` arrived (own loads)
    asm volatile("s_waitcnt lgkmcnt(0)" ::: "memory");         // prev-phase reads delivered
    __builtin_amdgcn_s_barrier();                              // all waves: data ready, reads retired
    asm volatile("" ::: "memory");                             // no mem-op hoist above barrier

    bf16x8 a0[4], b0[4];
#pragma unroll
    for (int mi = 0; mi < 4; ++mi)
        a0[mi] = *reinterpret_cast<const bf16x8*>(At + (wm * 128 + mi * 16 + fr) * 64 + sp * 16);
#pragma unroll
    for (int ni = 0; ni < 4; ++ni)
        b0[ni] = *reinterpret_cast<const bf16x8*>(Bt + (wn * 64 + ni * 16 + fr) * 64 + sp * 16);

    if (DOSTAGE) {  // stage A of tile buf+3 (ring slot (buf+3)&3)
        char* dA = ldsA + ((buf + 3) & 3) * 16384 + wave * 1024;
        GLD(aP0, dA);
        GLD(aP1, dA + 8192);
        aP0 += 64; aP1 += 64;
    }

    __builtin_amdgcn_s_setprio(1);
#pragma unroll
    for (int mi = 0; mi < 4; ++mi)
#pragma unroll
        for (int ni = 0; ni < 4; ++ni)
            acc[mi][ni] = __builtin_amdgcn_mfma_f32_16x16x32_bf16(a0[mi], b0[ni], acc[mi][ni], 0, 0, 0);
    __builtin_amdgcn_s_setprio(0);

    // ---- phase 1 ----
    asm volatile("s_waitcnt lgkmcnt(0)" ::: "memory");
    __builtin_amdgcn_s_barrier();
    asm volatile("" ::: "memory");

    bf16x8 a1[4];
#pragma unroll
    for (int mi = 0; mi < 4; ++mi)
        a1[mi] = *reinterpret_cast<const bf16x8*>(At + (wm * 128 + 64 + mi * 16 + fr) * 64 + sp * 16);

    if (DOSTAGE) {  // stage B of tile buf+3
        char* dB = ldsB + ((buf + 3) & 3) * 16384 + wave * 1024;
        GLD(bP0, dB);
        GLD(bP1, dB + 8192);
        bP0 += 64; bP1 += 64;
    }

    __builtin_amdgcn_s_setprio(1);
#pragma unroll
    for (int mi = 0; mi < 4; ++mi)
#pragma unroll
        for (int ni = 0; ni < 4; ++ni)
            acc[4 + mi][ni] = __builtin_amdgcn_mfma_f32_16x16x32_bf16(a1[mi], b0[ni], acc[4 + mi][ni], 0, 0, 0);
    __builtin_amdgcn_s_setprio(0);
}

__global__ __launch_bounds__(512, 2) void gemm_bt(const __hip_bfloat16* __restrict__ A,
                                                  const __hip_bfloat16* __restrict__ B,
                                                  float* __restrict__ C) {
    __shared__ __align__(16) char lds[131072];
    char* ldsA = (char*)lds;
    char* ldsB = (char*)lds + 65536;

    const int tid  = threadIdx.x;
    const int lane = tid & 63;
    const int wave = tid >> 6;
    const int wm = wave >> 2;          // 0..1
    const int wn = wave & 3;           // 0..3
    const int fr = lane & 15;
    const int sp = (lane >> 4) ^ ((fr >> 1) & 3);   // physical k-slot for ds_read

    // bijective XCD swizzle: 1024 wgs, 128 per XCD (4 tile-rows x 32 cols)
    const int bid = blockIdx.x;
    const int swz = (bid & 7) * 128 + (bid >> 3);
    const int tm = swz >> 5, tn = swz & 31;

    // per-thread staging source pointers (pre-swizzled k-offset)
    const char *aP0, *aP1, *bP0, *bP1;
    {
        int g = tid, r = g >> 2, sl = (g & 3) ^ ((r >> 1) & 3);
        aP0 = (const char*)A + ((size_t)(tm * 256 + r) * E_DIM + sl * 8) * 2;
        bP0 = (const char*)B + ((size_t)(tn * 256 + r) * E_DIM + sl * 8) * 2;
        g = tid + 512; r = g >> 2; sl = (g & 3) ^ ((r >> 1) & 3);
        aP1 = (const char*)A + ((size_t)(tm * 256 + r) * E_DIM + sl * 8) * 2;
        bP1 = (const char*)B + ((size_t)(tn * 256 + r) * E_DIM + sl * 8) * 2;
    }

    // prologue: stage tiles 0,1,2 into ring slots 0,1,2 (12 loads in flight)
#pragma unroll
    for (int t = 0; t < 3; ++t) {
        char* dA = ldsA + t * 16384 + wave * 1024;
        char* dB = ldsB + t * 16384 + wave * 1024;
        GLD(aP0, dA);
        GLD(aP1, dA + 8192);
        GLD(bP0, dB);
        GLD(bP1, dB + 8192);
        aP0 += 64; aP1 += 64; bP0 += 64; bP1 += 64;
    }

    f32x4 acc[8][4] = {};

    // main loop: compute tile kt, stage tile kt+3; vmcnt(8) keeps 2 tiles in flight
    for (int kt = 0; kt < NT - 3; ++kt)
        ktile<8, true >(ldsA, ldsB, kt & 3, wm, wn, fr, sp, wave, aP0, aP1, bP0, bP1, acc);
    // tail: drain 8 -> 4 -> 0, no staging
    ktile<8, false>(ldsA, ldsB, (NT - 3) & 3, wm, wn, fr, sp, wave, aP0, aP1, bP0, bP1, acc);
    ktile<4, false>(ldsA, ldsB, (NT - 2) & 3, wm, wn, fr, sp, wave, aP0, aP1, bP0, bP1, acc);
    ktile<0, false>(ldsA, ldsB, (NT - 1) & 3, wm, wn, fr, sp, wave, aP0, aP1, bP0, bP1, acc);

    // epilogue: C/D layout col = lane&15, row = (lane>>4)*4 + j
    const int crow0 = tm * 256 + wm * 128 + (lane >> 4) * 4;
    const int ccol0 = tn * 256 + wn * 64 + fr;
#pragma unroll
    for (int mi = 0; mi < 8; ++mi)
#pragma unroll
        for (int ni = 0; ni < 4; ++ni)
#pragma unroll
            for (int j = 0; j < 4; ++j)
                C[(size_t)(crow0 + mi * 16 + j) * N_DIM + (ccol0 + ni * 16)] = acc[mi][ni][j];
}

extern "C" void kernel_launch(void* const* d_in, const int* in_sizes, int n_in,
                              void* d_out, int out_size, void* d_ws, size_t ws_size,
                              hipStream_t stream) {
    const float* A = (const float*)d_in[0];   // DV2_H        [N, E]
    const float* B = (const float*)d_in[1];   // invDE_HT_DV2 [E, N]
    const float* W = (const float*)d_in[2];   // W            [E]
    float* C = (float*)d_out;                 // G            [N, N] fp32

    __hip_bfloat16* Abf  = (__hip_bfloat16*)d_ws;               // 32 MB
    __hip_bfloat16* Btbf = Abf + (size_t)N_DIM * E_DIM;         // 32 MB

    cvtA<<<(N_DIM * (size_t)E_DIM) / 8 / 256, 256, 0, stream>>>(A, Abf);
    dim3 tgrid(N_DIM / 32, E_DIM / 32);
    cvtB<<<tgrid, 256, 0, stream>>>(B, W, Btbf);
    gemm_bt<<<(N_DIM / 256) * (N_DIM / 256), 512, 0, stream>>>(Abf, Btbf, C);
}

// Round 3
// 309.137 us; speedup vs baseline: 1.3439x; 1.0383x over previous
//
#include <hip/hip_runtime.h>
#include <hip/hip_bf16.h>

#define N_DIM 8192
#define E_DIM 2048
#define NT 64            // K tiles of BK=32

typedef __bf16 bf16x8 __attribute__((ext_vector_type(8)));
typedef float  f32x4  __attribute__((ext_vector_type(4)));
typedef short  short8 __attribute__((ext_vector_type(8)));

#define GLD(gp, lp) __builtin_amdgcn_global_load_lds( \
    (const __attribute__((address_space(1))) void*)(gp), \
    (__attribute__((address_space(3))) void*)(lp), 16, 0, 0)

// ---------------- conversion: A fp32 [N,E] -> bf16 [N,E] ----------------
__global__ __launch_bounds__(256) void cvtA(const float* __restrict__ A,
                                            __hip_bfloat16* __restrict__ Abf) {
    size_t i = ((size_t)blockIdx.x * 256 + threadIdx.x) * 8;
    float4 f0 = *reinterpret_cast<const float4*>(A + i);
    float4 f1 = *reinterpret_cast<const float4*>(A + i + 4);
    union { short8 s8; __hip_bfloat16 h[8]; } u;
    u.h[0] = __float2bfloat16(f0.x);
    u.h[1] = __float2bfloat16(f0.y);
    u.h[2] = __float2bfloat16(f0.z);
    u.h[3] = __float2bfloat16(f0.w);
    u.h[4] = __float2bfloat16(f1.x);
    u.h[5] = __float2bfloat16(f1.y);
    u.h[6] = __float2bfloat16(f1.z);
    u.h[7] = __float2bfloat16(f1.w);
    *reinterpret_cast<short8*>(&Abf[i]) = u.s8;
}

// ------- scale+transpose: Bt[n,e] = W[e] * B[e,n], fp32 -> bf16 ---------
__global__ __launch_bounds__(256) void cvtB(const float* __restrict__ B,
                                            const float* __restrict__ W,
                                            __hip_bfloat16* __restrict__ Bt) {
    __shared__ float tile[32][33];
    const int tx = threadIdx.x & 31;
    const int ty = threadIdx.x >> 5;
    const int n0 = blockIdx.x * 32;
    const int e0 = blockIdx.y * 32;
#pragma unroll
    for (int r = 0; r < 4; ++r) {
        int e = e0 + ty + r * 8;
        tile[ty + r * 8][tx] = B[(size_t)e * N_DIM + n0 + tx] * W[e];
    }
    __syncthreads();
#pragma unroll
    for (int r = 0; r < 4; ++r) {
        int n = n0 + ty + r * 8;
        Bt[(size_t)n * E_DIM + e0 + tx] = __float2bfloat16(tile[tx][ty + r * 8]);
    }
}

// ---------------- GEMM: C[N,N] = Abf[N,E] * Btbf[N,E]^T ----------------
// 256x256 tile, BK=32, 8 waves (2Mx4N), 4-deep LDS ring (128 KiB), counted
// vmcnt, XOR slot swizzle, setprio, and REGISTER READ-AHEAD: each phase's
// MFMA consumes fragments ds_read during the PREVIOUS phase, so the LDS
// latency hides under the previous MFMA cluster + barrier wait.

template<bool STG, int VM, bool LAST>
__device__ __forceinline__ void ktile(char* ldsA, char* ldsB, int kt,
    int wm, int wn, int fr, int sp, int wave,
    const char*& aP0, const char*& aP1, const char*& bP0, const char*& bP1,
    bf16x8 (&alo)[4], bf16x8 (&ahi)[4], bf16x8 (&bcur)[4], bf16x8 (&bnxt)[4],
    f32x4 (&acc)[8][4])
{
    const int buf = kt & 3;
    const char* At = ldsA + buf * 16384;

    // ---- phase 0: MFMA(a_lo, b) [loaded last phase]; read a_hi(kt) ----
    asm volatile("s_waitcnt lgkmcnt(0)" ::: "memory");   // prev-phase reads landed
    __builtin_amdgcn_s_barrier();                        // WAR: all waves' reads of old slot retired
    __builtin_amdgcn_sched_barrier(0);
    if (STG) {  // stage A of tile kt+3 into ring slot (kt+3)&3
        char* dA = ldsA + ((buf + 3) & 3) * 16384 + wave * 1024;
        GLD(aP0, dA);
        GLD(aP1, dA + 8192);
        aP0 += 64; aP1 += 64;
    }
#pragma unroll
    for (int mi = 0; mi < 4; ++mi)
        ahi[mi] = *reinterpret_cast<const bf16x8*>(At + (wm * 128 + 64 + mi * 16 + fr) * 64 + sp * 16);
    __builtin_amdgcn_sched_barrier(0);                   // reads stay above MFMA
    __builtin_amdgcn_s_setprio(1);
#pragma unroll
    for (int mi = 0; mi < 4; ++mi)
#pragma unroll
        for (int ni = 0; ni < 4; ++ni)
            acc[mi][ni] = __builtin_amdgcn_mfma_f32_16x16x32_bf16(alo[mi], bcur[ni], acc[mi][ni], 0, 0, 0);
    __builtin_amdgcn_s_setprio(0);

    // ---- phase 1: MFMA(a_hi, b); read a_lo(kt+1), b_nxt(kt+1) ----
    asm volatile("s_waitcnt lgkmcnt(0)" ::: "memory");   // a_hi landed
    asm volatile("s_waitcnt vmcnt(%0)" :: "n"(VM) : "memory"); // tile kt+1 resident
    __builtin_amdgcn_s_barrier();
    __builtin_amdgcn_sched_barrier(0);
    if (STG) {  // stage B of tile kt+3
        char* dB = ldsB + ((buf + 3) & 3) * 16384 + wave * 1024;
        GLD(bP0, dB);
        GLD(bP1, dB + 8192);
        bP0 += 64; bP1 += 64;
    }
    if (!LAST) {
        const char* An = ldsA + ((kt + 1) & 3) * 16384;
        const char* Bn = ldsB + ((kt + 1) & 3) * 16384;
#pragma unroll
        for (int mi = 0; mi < 4; ++mi)
            alo[mi] = *reinterpret_cast<const bf16x8*>(An + (wm * 128 + mi * 16 + fr) * 64 + sp * 16);
#pragma unroll
        for (int ni = 0; ni < 4; ++ni)
            bnxt[ni] = *reinterpret_cast<const bf16x8*>(Bn + (wn * 64 + ni * 16 + fr) * 64 + sp * 16);
    }
    __builtin_amdgcn_sched_barrier(0);
    __builtin_amdgcn_s_setprio(1);
#pragma unroll
    for (int mi = 0; mi < 4; ++mi)
#pragma unroll
        for (int ni = 0; ni < 4; ++ni)
            acc[4 + mi][ni] = __builtin_amdgcn_mfma_f32_16x16x32_bf16(ahi[mi], bcur[ni], acc[4 + mi][ni], 0, 0, 0);
    __builtin_amdgcn_s_setprio(0);
}

__global__ __launch_bounds__(512, 2) void gemm_bt(const __hip_bfloat16* __restrict__ A,
                                                  const __hip_bfloat16* __restrict__ B,
                                                  float* __restrict__ C) {
    __shared__ __align__(16) char lds[131072];
    char* ldsA = (char*)lds;
    char* ldsB = (char*)lds + 65536;

    const int tid  = threadIdx.x;
    const int lane = tid & 63;
    const int wave = tid >> 6;
    const int wm = wave >> 2;          // 0..1
    const int wn = wave & 3;           // 0..3
    const int fr = lane & 15;
    const int sp = (lane >> 4) ^ ((fr >> 1) & 3);   // physical k-slot for ds_read

    // bijective XCD swizzle: 1024 wgs, 128 per XCD (4 tile-rows x 32 cols)
    const int bid = blockIdx.x;
    const int swz = (bid & 7) * 128 + (bid >> 3);
    const int tm = swz >> 5, tn = swz & 31;

    // per-thread staging source pointers (pre-swizzled k-offset)
    const char *aP0, *aP1, *bP0, *bP1;
    {
        int g = tid, r = g >> 2, sl = (g & 3) ^ ((r >> 1) & 3);
        aP0 = (const char*)A + ((size_t)(tm * 256 + r) * E_DIM + sl * 8) * 2;
        bP0 = (const char*)B + ((size_t)(tn * 256 + r) * E_DIM + sl * 8) * 2;
        g = tid + 512; r = g >> 2; sl = (g & 3) ^ ((r >> 1) & 3);
        aP1 = (const char*)A + ((size_t)(tm * 256 + r) * E_DIM + sl * 8) * 2;
        bP1 = (const char*)B + ((size_t)(tn * 256 + r) * E_DIM + sl * 8) * 2;
    }

    // prologue: stage tiles 0,1,2 into ring slots 0,1,2 (12 loads in flight)
#pragma unroll
    for (int t = 0; t < 3; ++t) {
        char* dA = ldsA + t * 16384 + wave * 1024;
        char* dB = ldsB + t * 16384 + wave * 1024;
        GLD(aP0, dA);
        GLD(aP1, dA + 8192);
        GLD(bP0, dB);
        GLD(bP1, dB + 8192);
        aP0 += 64; aP1 += 64; bP0 += 64; bP1 += 64;
    }

    f32x4 acc[8][4] = {};
    bf16x8 alo[4], ahi[4], bA[4], bB[4];

    // prologue reads: a_lo(0), b(0) -> bA
    asm volatile("s_waitcnt vmcnt(8)" ::: "memory");     // tile 0's 4 loads done
    __builtin_amdgcn_s_barrier();
    __builtin_amdgcn_sched_barrier(0);
#pragma unroll
    for (int mi = 0; mi < 4; ++mi)
        alo[mi] = *reinterpret_cast<const bf16x8*>(ldsA + (wm * 128 + mi * 16 + fr) * 64 + sp * 16);
#pragma unroll
    for (int ni = 0; ni < 4; ++ni)
        bA[ni] = *reinterpret_cast<const bf16x8*>(ldsB + (wn * 64 + ni * 16 + fr) * 64 + sp * 16);

    // main loop, 2-tile unrolled for compile-time b ping-pong (rule 20)
    for (int kt = 0; kt < 60; kt += 2) {
        ktile<true, 6, false>(ldsA, ldsB, kt,     wm, wn, fr, sp, wave, aP0, aP1, bP0, bP1, alo, ahi, bA, bB, acc);
        ktile<true, 6, false>(ldsA, ldsB, kt + 1, wm, wn, fr, sp, wave, aP0, aP1, bP0, bP1, alo, ahi, bB, bA, acc);
    }
    // tail: tiles 60..63, drain vmcnt 6 -> 4 -> 0
    ktile<true,  6, false>(ldsA, ldsB, 60, wm, wn, fr, sp, wave, aP0, aP1, bP0, bP1, alo, ahi, bA, bB, acc);
    ktile<false, 4, false>(ldsA, ldsB, 61, wm, wn, fr, sp, wave, aP0, aP1, bP0, bP1, alo, ahi, bB, bA, acc);
    ktile<false, 0, false>(ldsA, ldsB, 62, wm, wn, fr, sp, wave, aP0, aP1, bP0, bP1, alo, ahi, bA, bB, acc);
    ktile<false, 0, true >(ldsA, ldsB, 63, wm, wn, fr, sp, wave, aP0, aP1, bP0, bP1, alo, ahi, bB, bA, acc);

    // epilogue: C/D layout col = lane&15, row = (lane>>4)*4 + j
    const int crow0 = tm * 256 + wm * 128 + (lane >> 4) * 4;
    const int ccol0 = tn * 256 + wn * 64 + fr;
#pragma unroll
    for (int mi = 0; mi < 8; ++mi)
#pragma unroll
        for (int ni = 0; ni < 4; ++ni)
#pragma unroll
            for (int j = 0; j < 4; ++j)
                C[(size_t)(crow0 + mi * 16 + j) * N_DIM + (ccol0 + ni * 16)] = acc[mi][ni][j];
}

extern "C" void kernel_launch(void* const* d_in, const int* in_sizes, int n_in,
                              void* d_out, int out_size, void* d_ws, size_t ws_size,
                              hipStream_t stream) {
    const float* A = (const float*)d_in[0];   // DV2_H        [N, E]
    const float* B = (const float*)d_in[1];   // invDE_HT_DV2 [E, N]
    const float* W = (const float*)d_in[2];   // W            [E]
    float* C = (float*)d_out;                 // G            [N, N] fp32

    __hip_bfloat16* Abf  = (__hip_bfloat16*)d_ws;               // 32 MB
    __hip_bfloat16* Btbf = Abf + (size_t)N_DIM * E_DIM;         // 32 MB

    cvtA<<<(N_DIM * (size_t)E_DIM) / 8 / 256, 256, 0, stream>>>(A, Abf);
    dim3 tgrid(N_DIM / 32, E_DIM / 32);
    cvtB<<<tgrid, 256, 0, stream>>>(B, W, Btbf);
    gemm_bt<<<(N_DIM / 256) * (N_DIM / 256), 512, 0, stream>>>(Abf, Btbf, C);
}